// Round 15
// baseline (200.555 us; speedup 1.0000x reference)
//
#include <hip/hip_runtime.h>
#include <hip/hip_bf16.h>
#include <stdint.h>

// CrossAttention2d: n=16, c=1024, h=w=32 (hw=1024), S=256, c_enc=768, H=16, d=64.
// R15 = R14 (196.1 us) with attention processing TWO q-tiles per block:
// K+V staged once, tile-A chain, re-stage K (P aliased it) overlapped with
// tile-B Q loads, tile-B chain. Staging per 2 tiles: 128 -> 96 KB.
// GEMMs byte-for-byte R8/R14.

typedef __bf16 bf16x8 __attribute__((ext_vector_type(8)));
typedef __bf16 bf16x4 __attribute__((ext_vector_type(4)));
typedef float f32x4 __attribute__((ext_vector_type(4)));

#define VMCNT(n) asm volatile("s_waitcnt vmcnt(" #n ")" ::: "memory")

__device__ __forceinline__ void gload_lds16(const void* g, void* l) {
  __builtin_amdgcn_global_load_lds(
      (const __attribute__((address_space(1))) void*)(uintptr_t)g,
      (__attribute__((address_space(3))) void*)(unsigned int)(uintptr_t)l,
      16, 0, 0);
}

__device__ __forceinline__ f32x4 mfma16(bf16x8 a, bf16x8 b, f32x4 c) {
  return __builtin_amdgcn_mfma_f32_16x16x32_bf16(a, b, c, 0, 0, 0);
}

// ---------- fused LN: stats + normalize + transpose -> ndT[n][p][c] bf16 ----
__global__ __launch_bounds__(1024) void ln_fused_kernel(
    const float* __restrict__ x, const float* __restrict__ gamma,
    const float* __restrict__ beta, __bf16* __restrict__ ndT) {
  int p0 = blockIdx.x << 6;
  int n = blockIdx.y;
  int t = threadIdx.x;

  __shared__ f32x4 ls[64][16];
  __shared__ f32x4 ls2[64][16];
  __shared__ float lmu[64], lrs[64];
  __shared__ float tile[4][64][65];

  // phase 1: per-pixel sums over all 1024 channels
  {
    int pl4 = t & 15;
    int cg = t >> 4;
    const f32x4* xp = (const f32x4*)(x + ((size_t)n << 20) + p0);
    f32x4 s = {0.f, 0.f, 0.f, 0.f}, s2 = {0.f, 0.f, 0.f, 0.f};
#pragma unroll
    for (int i = 0; i < 16; ++i) {
      int c = cg + (i << 6);
      f32x4 v = xp[(c << 8) + pl4];
      s += v;
      s2 += v * v;
    }
    ls[cg][pl4] = s;
    ls2[cg][pl4] = s2;
    __syncthreads();
    if (t < 64) {
      int q = t >> 4, p = t & 15;
      f32x4 a = {0.f, 0.f, 0.f, 0.f}, a2 = {0.f, 0.f, 0.f, 0.f};
#pragma unroll
      for (int i = 0; i < 16; ++i) {
        a += ls[(q << 4) + i][p];
        a2 += ls2[(q << 4) + i][p];
      }
      ls[q][p] = a;
      ls2[q][p] = a2;
    }
    __syncthreads();
    if (t < 16) {
      f32x4 tot = ls[0][t] + ls[1][t] + ls[2][t] + ls[3][t];
      f32x4 tot2 = ls2[0][t] + ls2[1][t] + ls2[2][t] + ls2[3][t];
      f32x4 m, r;
#pragma unroll
      for (int e = 0; e < 4; ++e) {
        float mm = tot[e] * (1.f / 1024.f);
        float var = tot2[e] * (1.f / 1024.f) - mm * mm;
        m[e] = mm;
        r[e] = rsqrtf(var + 1e-5f);
      }
      ((f32x4*)lmu)[t] = m;
      ((f32x4*)lrs)[t] = r;
    }
    __syncthreads();
  }

  // phase 2: normalize + transpose, 4 c-tiles in parallel per iteration
  int sub = t >> 8;
  int st = t & 255;
  int fc = st & 15;
  int rr = st >> 4;
  int cgp = st & 7;
  int pr = st >> 3;
  for (int it = 0; it < 4; ++it) {
    int c0 = (((it << 2) + sub) << 6);
    const float* xb = x + ((size_t)n << 20) + ((size_t)c0 << 10) + p0;
#pragma unroll
    for (int i = 0; i < 4; ++i) {
      int cl = (i << 4) + rr;
      f32x4 v = *(const f32x4*)(xb + ((size_t)cl << 10) + (fc << 2));
#pragma unroll
      for (int e = 0; e < 4; ++e) tile[sub][cl][(fc << 2) + e] = v[e];
    }
    float g[8], bb[8];
#pragma unroll
    for (int k = 0; k < 8; ++k) {
      g[k] = gamma[c0 + (cgp << 3) + k];
      bb[k] = beta[c0 + (cgp << 3) + k];
    }
    __syncthreads();
#pragma unroll
    for (int it2 = 0; it2 < 2; ++it2) {
      int pl = (it2 << 5) + pr;
      float m = lmu[pl], r = lrs[pl];
      bf16x8 o;
#pragma unroll
      for (int k = 0; k < 8; ++k)
        o[k] = (__bf16)((tile[sub][(cgp << 3) + k][pl] - m) * r * g[k] + bb[k]);
      *(bf16x8*)(ndT + ((size_t)((n << 10) + p0 + pl) << 10) + c0 + (cgp << 3)) = o;
    }
    __syncthreads();
  }
}

// ---------- enc LayerNorm (last dim 768) -> bf16 ----------
__global__ __launch_bounds__(256) void enc_ln_kernel(const float* __restrict__ enc,
    const float* __restrict__ gamma, const float* __restrict__ beta,
    __bf16* __restrict__ out) {
  int s = blockIdx.x, n = blockIdx.y;
  size_t base = ((size_t)n * 256 + s) * 768;
  int t = threadIdx.x;
  float v0 = enc[base + t], v1 = enc[base + t + 256], v2 = enc[base + t + 512];
  float sum = v0 + v1 + v2, sq = v0 * v0 + v1 * v1 + v2 * v2;
#pragma unroll
  for (int off = 32; off; off >>= 1) {
    sum += __shfl_down(sum, off);
    sq  += __shfl_down(sq, off);
  }
  __shared__ float red[8];
  int w = t >> 6;
  if ((t & 63) == 0) { red[w] = sum; red[4 + w] = sq; }
  __syncthreads();
  float tot  = red[0] + red[1] + red[2] + red[3];
  float tot2 = red[4] + red[5] + red[6] + red[7];
  float m = tot * (1.f / 768.f);
  float var = tot2 * (1.f / 768.f) - m * m;
  float rs = rsqrtf(var + 1e-5f);
  out[base + t]       = (__bf16)((v0 - m) * rs * gamma[t] + beta[t]);
  out[base + t + 256] = (__bf16)((v1 - m) * rs * gamma[t + 256] + beta[t + 256]);
  out[base + t + 512] = (__bf16)((v2 - m) * rs * gamma[t + 512] + beta[t + 512]);
}

// ---------- fp32 -> bf16 cast, 3 tensors in one dispatch ----------
__global__ __launch_bounds__(256) void cast3_kernel(
    const float* __restrict__ a, __bf16* __restrict__ oa, int na,
    const float* __restrict__ b, __bf16* __restrict__ ob, int nb,
    const float* __restrict__ c, __bf16* __restrict__ oc, int nc) {
  int stride = gridDim.x * 256;
  int total = na + nb + nc;
  for (int i = blockIdx.x * 256 + threadIdx.x; i < total; i += stride) {
    if (i < na)            oa[i] = (__bf16)a[i];
    else if (i < na + nb)  ob[i - na] = (__bf16)b[i - na];
    else                   oc[i - na - nb] = (__bf16)c[i - na - nb];
  }
}

// ---------- V transpose: kv[n][s][1024+c] -> vT[n][c][s] ----------
__global__ __launch_bounds__(256) void v_transpose_kernel(const __bf16* __restrict__ kv,
                                                          __bf16* __restrict__ vT) {
  int h = blockIdx.x, n = blockIdx.y;
  __shared__ __bf16 tile[64][264];
  int t = threadIdx.x;
  const __bf16* src = kv + ((size_t)n << 19) + 1024 + (h << 6);
#pragma unroll
  for (int i = 0; i < 8; ++i) {
    int s = (i << 5) + (t >> 3);
    int d8 = (t & 7) << 3;
    bf16x8 v = *(const bf16x8*)(src + ((size_t)s << 11) + d8);
#pragma unroll
    for (int j = 0; j < 8; ++j) tile[d8 + j][s] = v[j];
  }
  __syncthreads();
  __bf16* dst = vT + (((size_t)(n << 10) + (h << 6)) << 8);
  int d = t >> 2, s0 = (t & 3) << 6;
#pragma unroll
  for (int j = 0; j < 8; ++j)
    *(bf16x8*)(dst + ((size_t)d << 8) + s0 + (j << 3)) = *(const bf16x8*)&tile[d][s0 + (j << 3)];
}

// ---------- gemm128 (R8 exact): C = A * Bt^T (+bias, +resid) ----------
template <int EPI>
__global__ __launch_bounds__(256, 2) void gemm128_kernel(
    const __bf16* __restrict__ A, const __bf16* __restrict__ Bt,
    const float* __restrict__ bias, const float* __restrict__ resid,
    void* __restrict__ Cout, int M, int N, int K,
    size_t sA, size_t sB, size_t sC, size_t sR) {
  int gx = gridDim.x, gy = gridDim.y;
  int lin = blockIdx.x + gx * (blockIdx.y + gy * blockIdx.z);
  int nwg = gx * gy * (int)gridDim.z;
  int cpx = nwg >> 3;
  int sid = (lin & 7) * cpx + (lin >> 3);
  int bx = sid % gx;
  int rem = sid / gx;
  int by = rem % gy;
  int bz = rem / gy;

  int n0 = bx << 7;
  int m0 = by << 7;
  const __bf16* Ab = A + sA * bz;
  const __bf16* Bb = Bt + sB * bz;

  int tid = threadIdx.x;
  int w = tid >> 6, lane = tid & 63;
  int l15 = lane & 15, hi = lane >> 4;
  int wm = w >> 1, wn = w & 1;

  __shared__ __align__(16) __bf16 lA[2][128 * 64];
  __shared__ __align__(16) __bf16 lB[2][128 * 64];

  f32x4 acc[4][4] = {};
  int xk = (l15 & 7) << 3;
  int NT = K >> 6;

  auto stage = [&](int buf, int kt) {
#pragma unroll
    for (int j = 0; j < 4; ++j) {
      int e = (j << 11) + (tid << 3);
      int r = e >> 6, c = e & 63;
      int cs = c ^ ((r & 7) << 3);
      gload_lds16(Ab + (size_t)(m0 + r) * K + kt + cs, &lA[buf][e]);
    }
#pragma unroll
    for (int j = 0; j < 4; ++j) {
      int e = (j << 11) + (tid << 3);
      int r = e >> 6, c = e & 63;
      int cs = c ^ ((r & 7) << 3);
      gload_lds16(Bb + (size_t)(n0 + r) * K + kt + cs, &lB[buf][e]);
    }
  };

  stage(0, 0);   // prologue

  for (int t = 0; t < NT; ++t) {
    int cur = t & 1;
    if (t + 1 < NT) {
      stage(cur ^ 1, (t + 1) << 6);
      VMCNT(8);
    } else {
      VMCNT(0);
    }
    __builtin_amdgcn_s_barrier();
    __builtin_amdgcn_sched_barrier(0);

    const __bf16* lAb = lA[cur];
    const __bf16* lBb = lB[cur];
    __builtin_amdgcn_s_setprio(1);
#pragma unroll
    for (int kk = 0; kk < 2; ++kk) {
      int ko = ((kk << 5) + (hi << 3)) ^ xk;
      bf16x8 af[4], bfr[4];
#pragma unroll
      for (int mi = 0; mi < 4; ++mi)
        af[mi] = *(const bf16x8*)&lAb[(((wm << 6) + (mi << 4) + l15) << 6) + ko];
#pragma unroll
      for (int ni = 0; ni < 4; ++ni)
        bfr[ni] = *(const bf16x8*)&lBb[(((wn << 6) + (ni << 4) + l15) << 6) + ko];
#pragma unroll
      for (int mi = 0; mi < 4; ++mi)
#pragma unroll
        for (int ni = 0; ni < 4; ++ni)
          acc[mi][ni] = mfma16(af[mi], bfr[ni], acc[mi][ni]);
    }
    __builtin_amdgcn_s_setprio(0);
    __builtin_amdgcn_sched_barrier(0);
    __builtin_amdgcn_s_barrier();
  }

#pragma unroll
  for (int mi = 0; mi < 4; ++mi) {
#pragma unroll
    for (int ni = 0; ni < 4; ++ni) {
      int col = n0 + (wn << 6) + (ni << 4) + l15;
      int rbase = m0 + (wm << 6) + (mi << 4) + (hi << 2);
      if (EPI == 0) {
        float bb = bias[col];
        __bf16* C = (__bf16*)Cout + sC * bz;
#pragma unroll
        for (int j = 0; j < 4; ++j)
          C[(size_t)(rbase + j) * N + col] = (__bf16)(acc[mi][ni][j] + bb);
      } else {
        float* C = (float*)Cout + sC * bz;
        const float* R = resid + sR * bz;
#pragma unroll
        for (int j = 0; j < 4; ++j) {
          int row = rbase + j;
          C[(size_t)row * N + col] = acc[mi][ni][j] + bias[row] + R[(size_t)row * N + col];
        }
      }
    }
  }
}

// ---------- attention: 2 q-tiles per block, K/V staged once + K re-stage ----
// Block (h, qb2, n), grid 2048. Chain per tile = R8-exact (swapped QK^T,
// log2 softmax via __builtin_amdgcn_exp2f, P aliases K, PV from LDS V^T).
// Between tiles: post-PV __syncthreads frees P region; K re-staged (8 gloads)
// while tile-B's Q loads issue; VMCNT(0)+raw barrier gates tile-B's QK.
__global__ __launch_bounds__(256, 2) void attn_kernel(
    const __bf16* __restrict__ QT,   // [n][1024][1024]
    const __bf16* __restrict__ kv,   // [n][256][2048] (K part: cols 0..1023)
    const __bf16* __restrict__ vT,   // [n][1024][256]
    const int* __restrict__ padding, // [n][256]
    __bf16* __restrict__ yT) {       // [n][1024][1024]
  int h = blockIdx.x, qb2 = blockIdx.y, n = blockIdx.z;
  int tid = threadIdx.x;
  int w = tid >> 6, lane = tid & 63;
  int l15 = lane & 15, hi = lane >> 4;
  int xk = (l15 & 7) << 3;

  __shared__ __align__(16) __bf16 lKP[256 * 64];  // K; later P [64 q][256 keys]
  __shared__ __align__(16) __bf16 lVt[64 * 256];  // V^T [64 d][256 keys]
  __shared__ __align__(16) float lpad[256];

  const __bf16* kvb = kv + ((size_t)n << 19);
  const __bf16* vtb = vT + (((size_t)(n << 10) + (h << 6)) << 8);

  // initial stage: K + V^T
#pragma unroll
  for (int i = 0; i < 8; ++i) {
    int e = ((i << 8) + tid) << 3;
    int r = e >> 6, c = e & 63;
    int cs = c ^ ((r & 7) << 3);
    gload_lds16(kvb + ((size_t)r << 11) + (h << 6) + cs, &lKP[e]);
  }
#pragma unroll
  for (int i = 0; i < 8; ++i) {
    int e = ((i << 8) + tid) << 3;
    int r = e >> 8, c = e & 255;
    int cs = c ^ ((r & 7) << 3);
    gload_lds16(vtb + ((size_t)r << 8) + cs, &lVt[e]);
  }
  lpad[tid] = 14426.95041f * (float)padding[(n << 8) + tid];  // 10000*log2(e)

  const float sc = 0.18033688f;   // 0.125 * log2(e)

#pragma unroll 1
  for (int half = 0; half < 2; ++half) {
    int q0w = (qb2 << 7) + (half << 6) + (w << 4);
    const __bf16* qsrc = QT + ((size_t)((n << 10) + q0w + l15) << 10) + (h << 6) + (hi << 3);
    bf16x8 bq0 = *(const bf16x8*)qsrc;
    bf16x8 bq1 = *(const bf16x8*)(qsrc + 32);

    if (half == 0) {
      __syncthreads();               // drains initial gload_lds (vmcnt 0) + barrier
    } else {
      VMCNT(0);                      // K re-stage landed
      __builtin_amdgcn_s_barrier();
      __builtin_amdgcn_sched_barrier(0);
    }

    // S^T = K Q^T : lane(hi,l15) holds S[key=16kg+4hi+j][q=q0w+l15]
    f32x4 sa[16];
#pragma unroll
    for (int kg = 0; kg < 16; ++kg) {
      const __bf16* krow = &lKP[((kg << 4) + l15) << 6];
      bf16x8 a0 = *(const bf16x8*)&krow[(hi << 3) ^ xk];
      bf16x8 a1 = *(const bf16x8*)&krow[(32 + (hi << 3)) ^ xk];
      f32x4 z = {0.f, 0.f, 0.f, 0.f};
      z = mfma16(a0, bq0, z);
      sa[kg] = mfma16(a1, bq1, z);
    }

    // masked softmax in log2 domain
    float mx0 = -3.4e38f, mx1 = -3.4e38f;
#pragma unroll
    for (int kg = 0; kg < 16; ++kg) {
      f32x4 pm = *(const f32x4*)&lpad[(kg << 4) + (hi << 2)];
#pragma unroll
      for (int j = 0; j < 4; ++j)
        sa[kg][j] = fmaf(sa[kg][j], sc, -pm[j]);
      mx0 = fmaxf(mx0, fmaxf(sa[kg][0], sa[kg][1]));
      mx1 = fmaxf(mx1, fmaxf(sa[kg][2], sa[kg][3]));
    }
    float mx = fmaxf(mx0, mx1);
    mx = fmaxf(mx, __shfl_xor(mx, 16));
    mx = fmaxf(mx, __shfl_xor(mx, 32));
    float sum = 0.f;
#pragma unroll
    for (int kg = 0; kg < 16; ++kg)
#pragma unroll
      for (int j = 0; j < 4; ++j) {
        float p = __builtin_amdgcn_exp2f(sa[kg][j] - mx);
        sa[kg][j] = p;
        sum += p;
      }
    sum += __shfl_xor(sum, 16);
    sum += __shfl_xor(sum, 32);
    float dinv = 1.f / sum;

    __syncthreads();          // all waves done reading K -> lKP becomes P

    __bf16* lP = &lKP[(((w << 4) + l15) << 8)];
#pragma unroll
    for (int kg = 0; kg < 16; ++kg) {
      bf16x4 pk;
#pragma unroll
      for (int j = 0; j < 4; ++j) pk[j] = (__bf16)sa[kg][j];
      *(bf16x4*)&lP[(((kg << 4) + (hi << 2)) ^ xk)] = pk;
    }

    f32x4 ya[4] = {};
#pragma unroll
    for (int kc = 0; kc < 8; ++kc) {
      bf16x8 pa = *(const bf16x8*)&lP[(((kc << 5) + (hi << 3)) ^ xk)];
#pragma unroll
      for (int nd = 0; nd < 4; ++nd) {
        bf16x8 vb = *(const bf16x8*)&lVt[(((nd << 4) + l15) << 8) + (((kc << 5) + (hi << 3)) ^ xk)];
        ya[nd] = mfma16(pa, vb, ya[nd]);
      }
    }

    float dq[4];
#pragma unroll
    for (int j = 0; j < 4; ++j) dq[j] = __shfl(dinv, (hi << 2) + j);

#pragma unroll
    for (int nd = 0; nd < 4; ++nd) {
      int d = (h << 6) + (nd << 4) + l15;
#pragma unroll
      for (int j = 0; j < 4; ++j) {
        int q = q0w + (hi << 2) + j;
        yT[((size_t)((n << 10) + q) << 10) + d] = (__bf16)(ya[nd][j] * dq[j]);
      }
    }

    if (half == 0) {
      __syncthreads();          // all waves done reading P (and V stays valid)
      // re-stage K into lKP for tile B (overlaps tile-B Q loads at loop top)
#pragma unroll
      for (int i = 0; i < 8; ++i) {
        int e = ((i << 8) + tid) << 3;
        int r = e >> 6, c = e & 63;
        int cs = c ^ ((r & 7) << 3);
        gload_lds16(kvb + ((size_t)r << 11) + (h << 6) + cs, &lKP[e]);
      }
    }
  }
}

extern "C" void kernel_launch(void* const* d_in, const int* in_sizes, int n_in,
                              void* d_out, int out_size, void* d_ws, size_t ws_size,
                              hipStream_t stream) {
  const float* x         = (const float*)d_in[0];
  const float* enc       = (const float*)d_in[1];
  const int*   padding   = (const int*)d_in[2];
  const float* gamma_dec = (const float*)d_in[3];
  const float* beta_dec  = (const float*)d_in[4];
  const float* gamma_enc = (const float*)d_in[5];
  const float* beta_enc  = (const float*)d_in[6];
  const float* Wq        = (const float*)d_in[7];
  const float* bq        = (const float*)d_in[8];
  const float* Wkv       = (const float*)d_in[9];
  const float* bkv       = (const float*)d_in[10];
  const float* Wo        = (const float*)d_in[11];
  const float* bo        = (const float*)d_in[12];
  float* out = (float*)d_out;

  char* ws = (char*)d_ws;
  __bf16* ndT  = (__bf16*)(ws);
  __bf16* yT   = (__bf16*)(ws);                 // reuse: ndT dead after Q-GEMM
  __bf16* QT   = (__bf16*)(ws + 33554432);
  __bf16* kvb  = (__bf16*)(ws + 67108864);
  __bf16* encn = (__bf16*)(ws + 83886080);
  __bf16* vT   = (__bf16*)(ws + 83886080);      // reuse: encn dead after kv-GEMM
  __bf16* WqB  = (__bf16*)(ws + 92274688);
  __bf16* WkvB = (__bf16*)(ws + 94371840);
  __bf16* WoB  = (__bf16*)(ws + 97517568);

  ln_fused_kernel<<<dim3(16, 16), 1024, 0, stream>>>(x, gamma_dec, beta_dec, ndT);
  enc_ln_kernel<<<dim3(256, 16), 256, 0, stream>>>(enc, gamma_enc, beta_enc, encn);
  cast3_kernel<<<1024, 256, 0, stream>>>(Wq, WqB, 1024 * 1024,
                                         Wkv, WkvB, 2048 * 768,
                                         Wo, WoB, 1024 * 1024);

  // QT[n][p][o] = ndT[n] @ Wq^T + bq
  gemm128_kernel<0><<<dim3(8, 8, 16), 256, 0, stream>>>(
      ndT, WqB, bq, nullptr, QT, 1024, 1024, 1024,
      (size_t)1024 * 1024, 0, (size_t)1024 * 1024, 0);
  // kv[n][s][j] = encn[n] @ Wkv^T + bkv  (M=256, N=2048, K=768)
  gemm128_kernel<0><<<dim3(16, 2, 16), 256, 0, stream>>>(
      encn, WkvB, bkv, nullptr, kvb, 256, 2048, 768,
      (size_t)256 * 768, 0, (size_t)256 * 2048, 0);

  v_transpose_kernel<<<dim3(16, 16), 256, 0, stream>>>(kvb, vT);

  attn_kernel<<<dim3(16, 8, 16), 256, 0, stream>>>(QT, kvb, vT, padding, yT);

  // out[n][o][p] = x + Wo @ y + bo   (A=WoB shared, Bt=yT per n)
  gemm128_kernel<1><<<dim3(8, 8, 16), 256, 0, stream>>>(
      WoB, yT, bo, x, out, 1024, 1024, 1024,
      0, (size_t)1024 * 1024, (size_t)1024 * 1024, (size_t)1024 * 1024);
}

// Round 17
// 191.475 us; speedup vs baseline: 1.0474x; 1.0474x over previous
//
#include <hip/hip_runtime.h>
#include <hip/hip_bf16.h>
#include <stdint.h>

// CrossAttention2d: n=16, c=1024, h=w=32 (hw=1024), S=256, c_enc=768, H=16, d=64.
// R17 = R16 with the aliasing bug fixed: kv's V-half is never materialized, so
// K-only kvK (8 MB) + vT (8 MB) pack into the old 16 MB kv slot -- no overlap
// with encn (R16's race: vT aliased encn while kv-GEMM blocks still read it).
// kv-GEMM EPI=2: K-half -> kvK (ldC=1024); V-half -> vT via staging-LDS
// transpose. T5 setprio on attn MFMA clusters. LN-fused + exp2 attn from R14.

typedef __bf16 bf16x8 __attribute__((ext_vector_type(8)));
typedef __bf16 bf16x4 __attribute__((ext_vector_type(4)));
typedef float f32x4 __attribute__((ext_vector_type(4)));

#define VMCNT(n) asm volatile("s_waitcnt vmcnt(" #n ")" ::: "memory")

__device__ __forceinline__ void gload_lds16(const void* g, void* l) {
  __builtin_amdgcn_global_load_lds(
      (const __attribute__((address_space(1))) void*)(uintptr_t)g,
      (__attribute__((address_space(3))) void*)(unsigned int)(uintptr_t)l,
      16, 0, 0);
}

__device__ __forceinline__ f32x4 mfma16(bf16x8 a, bf16x8 b, f32x4 c) {
  return __builtin_amdgcn_mfma_f32_16x16x32_bf16(a, b, c, 0, 0, 0);
}

// ---------- fused LN: stats + normalize + transpose -> ndT[n][p][c] bf16 ----
__global__ __launch_bounds__(1024) void ln_fused_kernel(
    const float* __restrict__ x, const float* __restrict__ gamma,
    const float* __restrict__ beta, __bf16* __restrict__ ndT) {
  int p0 = blockIdx.x << 6;
  int n = blockIdx.y;
  int t = threadIdx.x;

  __shared__ f32x4 ls[64][16];
  __shared__ f32x4 ls2[64][16];
  __shared__ float lmu[64], lrs[64];
  __shared__ float tile[4][64][65];

  {
    int pl4 = t & 15;
    int cg = t >> 4;
    const f32x4* xp = (const f32x4*)(x + ((size_t)n << 20) + p0);
    f32x4 s = {0.f, 0.f, 0.f, 0.f}, s2 = {0.f, 0.f, 0.f, 0.f};
#pragma unroll
    for (int i = 0; i < 16; ++i) {
      int c = cg + (i << 6);
      f32x4 v = xp[(c << 8) + pl4];
      s += v;
      s2 += v * v;
    }
    ls[cg][pl4] = s;
    ls2[cg][pl4] = s2;
    __syncthreads();
    if (t < 64) {
      int q = t >> 4, p = t & 15;
      f32x4 a = {0.f, 0.f, 0.f, 0.f}, a2 = {0.f, 0.f, 0.f, 0.f};
#pragma unroll
      for (int i = 0; i < 16; ++i) {
        a += ls[(q << 4) + i][p];
        a2 += ls2[(q << 4) + i][p];
      }
      ls[q][p] = a;
      ls2[q][p] = a2;
    }
    __syncthreads();
    if (t < 16) {
      f32x4 tot = ls[0][t] + ls[1][t] + ls[2][t] + ls[3][t];
      f32x4 tot2 = ls2[0][t] + ls2[1][t] + ls2[2][t] + ls2[3][t];
      f32x4 m, r;
#pragma unroll
      for (int e = 0; e < 4; ++e) {
        float mm = tot[e] * (1.f / 1024.f);
        float var = tot2[e] * (1.f / 1024.f) - mm * mm;
        m[e] = mm;
        r[e] = rsqrtf(var + 1e-5f);
      }
      ((f32x4*)lmu)[t] = m;
      ((f32x4*)lrs)[t] = r;
    }
    __syncthreads();
  }

  int sub = t >> 8;
  int st = t & 255;
  int fc = st & 15;
  int rr = st >> 4;
  int cgp = st & 7;
  int pr = st >> 3;
  for (int it = 0; it < 4; ++it) {
    int c0 = (((it << 2) + sub) << 6);
    const float* xb = x + ((size_t)n << 20) + ((size_t)c0 << 10) + p0;
#pragma unroll
    for (int i = 0; i < 4; ++i) {
      int cl = (i << 4) + rr;
      f32x4 v = *(const f32x4*)(xb + ((size_t)cl << 10) + (fc << 2));
#pragma unroll
      for (int e = 0; e < 4; ++e) tile[sub][cl][(fc << 2) + e] = v[e];
    }
    float g[8], bb[8];
#pragma unroll
    for (int k = 0; k < 8; ++k) {
      g[k] = gamma[c0 + (cgp << 3) + k];
      bb[k] = beta[c0 + (cgp << 3) + k];
    }
    __syncthreads();
#pragma unroll
    for (int it2 = 0; it2 < 2; ++it2) {
      int pl = (it2 << 5) + pr;
      float m = lmu[pl], r = lrs[pl];
      bf16x8 o;
#pragma unroll
      for (int k = 0; k < 8; ++k)
        o[k] = (__bf16)((tile[sub][(cgp << 3) + k][pl] - m) * r * g[k] + bb[k]);
      *(bf16x8*)(ndT + ((size_t)((n << 10) + p0 + pl) << 10) + c0 + (cgp << 3)) = o;
    }
    __syncthreads();
  }
}

// ---------- enc LayerNorm (last dim 768) -> bf16 ----------
__global__ __launch_bounds__(256) void enc_ln_kernel(const float* __restrict__ enc,
    const float* __restrict__ gamma, const float* __restrict__ beta,
    __bf16* __restrict__ out) {
  int s = blockIdx.x, n = blockIdx.y;
  size_t base = ((size_t)n * 256 + s) * 768;
  int t = threadIdx.x;
  float v0 = enc[base + t], v1 = enc[base + t + 256], v2 = enc[base + t + 512];
  float sum = v0 + v1 + v2, sq = v0 * v0 + v1 * v1 + v2 * v2;
#pragma unroll
  for (int off = 32; off; off >>= 1) {
    sum += __shfl_down(sum, off);
    sq  += __shfl_down(sq, off);
  }
  __shared__ float red[8];
  int w = t >> 6;
  if ((t & 63) == 0) { red[w] = sum; red[4 + w] = sq; }
  __syncthreads();
  float tot  = red[0] + red[1] + red[2] + red[3];
  float tot2 = red[4] + red[5] + red[6] + red[7];
  float m = tot * (1.f / 768.f);
  float var = tot2 * (1.f / 768.f) - m * m;
  float rs = rsqrtf(var + 1e-5f);
  out[base + t]       = (__bf16)((v0 - m) * rs * gamma[t] + beta[t]);
  out[base + t + 256] = (__bf16)((v1 - m) * rs * gamma[t + 256] + beta[t + 256]);
  out[base + t + 512] = (__bf16)((v2 - m) * rs * gamma[t + 512] + beta[t + 512]);
}

// ---------- fp32 -> bf16 cast, 3 tensors in one dispatch ----------
__global__ __launch_bounds__(256) void cast3_kernel(
    const float* __restrict__ a, __bf16* __restrict__ oa, int na,
    const float* __restrict__ b, __bf16* __restrict__ ob, int nb,
    const float* __restrict__ c, __bf16* __restrict__ oc, int nc) {
  int stride = gridDim.x * 256;
  int total = na + nb + nc;
  for (int i = blockIdx.x * 256 + threadIdx.x; i < total; i += stride) {
    if (i < na)            oa[i] = (__bf16)a[i];
    else if (i < na + nb)  ob[i - na] = (__bf16)b[i - na];
    else                   oc[i - na - nb] = (__bf16)c[i - na - nb];
  }
}

// ---------- gemm128: C[M][N] = A[M][K] * Bt[N][K]^T ----------
// K-loop R8-exact. EPI 0: bias[col], bf16 out (stride ldC).
// EPI 1: bias[row] + fp32 resid, fp32 out (stride ldC).
// EPI 2: K-half (n0<1024) -> EPI-0 store into kvK (ldC=1024);
//        V-half (n0>=1024) -> acc+bias via staging LDS bf16[128][136]
//        (transposed) -> coalesced bf16x8 stores to vT[n][c][s].
template <int EPI>
__global__ __launch_bounds__(256, 2) void gemm128_kernel(
    const __bf16* __restrict__ A, const __bf16* __restrict__ Bt,
    const float* __restrict__ bias, const float* __restrict__ resid,
    void* __restrict__ Cout, __bf16* __restrict__ vt,
    int M, int N, int K, int ldC,
    size_t sA, size_t sB, size_t sC, size_t sR) {
  // bijective XCD swizzle (nwg % 8 == 0 for all our grids)
  int gx = gridDim.x, gy = gridDim.y;
  int lin = blockIdx.x + gx * (blockIdx.y + gy * blockIdx.z);
  int nwg = gx * gy * (int)gridDim.z;
  int cpx = nwg >> 3;
  int sid = (lin & 7) * cpx + (lin >> 3);
  int bx = sid % gx;
  int rem = sid / gx;
  int by = rem % gy;
  int bz = rem / gy;

  int n0 = bx << 7;
  int m0 = by << 7;
  const __bf16* Ab = A + sA * bz;
  const __bf16* Bb = Bt + sB * bz;

  int tid = threadIdx.x;
  int w = tid >> 6, lane = tid & 63;
  int l15 = lane & 15, hi = lane >> 4;
  int wm = w >> 1, wn = w & 1;   // 2m x 2n wave grid; 64x64 out per wave

  // 64 KB staging; EPI=2 V-half reuses as bf16 [128][136] (34.8 KB)
  __shared__ __align__(16) __bf16 smem[2][2][128 * 64];

  f32x4 acc[4][4] = {};
  int xk = (l15 & 7) << 3;
  int NT = K >> 6;

  auto stage = [&](int buf, int kt) {
#pragma unroll
    for (int j = 0; j < 4; ++j) {
      int e = (j << 11) + (tid << 3);
      int r = e >> 6, c = e & 63;
      int cs = c ^ ((r & 7) << 3);
      gload_lds16(Ab + (size_t)(m0 + r) * K + kt + cs, &smem[0][buf][e]);
    }
#pragma unroll
    for (int j = 0; j < 4; ++j) {
      int e = (j << 11) + (tid << 3);
      int r = e >> 6, c = e & 63;
      int cs = c ^ ((r & 7) << 3);
      gload_lds16(Bb + (size_t)(n0 + r) * K + kt + cs, &smem[1][buf][e]);
    }
  };

  stage(0, 0);   // prologue

  for (int t = 0; t < NT; ++t) {
    int cur = t & 1;
    if (t + 1 < NT) {
      stage(cur ^ 1, (t + 1) << 6);  // trailing barrier of t-1 freed buf cur^1
      VMCNT(8);                      // wait tile t's 8 loads; keep 8 in flight
    } else {
      VMCNT(0);
    }
    __builtin_amdgcn_s_barrier();
    __builtin_amdgcn_sched_barrier(0);

    const __bf16* lAb = smem[0][cur];
    const __bf16* lBb = smem[1][cur];
    __builtin_amdgcn_s_setprio(1);
#pragma unroll
    for (int kk = 0; kk < 2; ++kk) {
      int ko = ((kk << 5) + (hi << 3)) ^ xk;
      bf16x8 af[4], bfr[4];
#pragma unroll
      for (int mi = 0; mi < 4; ++mi)
        af[mi] = *(const bf16x8*)&lAb[(((wm << 6) + (mi << 4) + l15) << 6) + ko];
#pragma unroll
      for (int ni = 0; ni < 4; ++ni)
        bfr[ni] = *(const bf16x8*)&lBb[(((wn << 6) + (ni << 4) + l15) << 6) + ko];
#pragma unroll
      for (int mi = 0; mi < 4; ++mi)
#pragma unroll
        for (int ni = 0; ni < 4; ++ni)
          acc[mi][ni] = mfma16(af[mi], bfr[ni], acc[mi][ni]);
    }
    __builtin_amdgcn_s_setprio(0);
    __builtin_amdgcn_sched_barrier(0);
    __builtin_amdgcn_s_barrier();
  }

  if (EPI == 2 && n0 >= 1024) {
    // V-half: transpose via LDS, write vT[n][c][s] coalesced
    __syncthreads();                 // staging LDS free for reuse
    __bf16* tl2 = (__bf16*)smem;     // [128 c][136 stride] bf16
#pragma unroll
    for (int mi = 0; mi < 4; ++mi)
#pragma unroll
      for (int ni = 0; ni < 4; ++ni) {
        int col = (wn << 6) + (ni << 4) + l15;         // c_local
        float bb = bias[n0 + col];
        int rb = (wm << 6) + (mi << 4) + (hi << 2);    // s_local
        bf16x4 pk;
#pragma unroll
        for (int j = 0; j < 4; ++j) pk[j] = (__bf16)(acc[mi][ni][j] + bb);
        *(bf16x4*)&tl2[col * 136 + rb] = pk;
      }
    __syncthreads();
    int c_local = tid >> 1;
    int so = (tid & 1) << 6;
    __bf16* vdst = vt + ((size_t)bz << 18) + (size_t)(n0 - 1024 + c_local) * 256 + m0 + so;
    const __bf16* vsrc = &tl2[c_local * 136 + so];
#pragma unroll
    for (int k8 = 0; k8 < 8; ++k8)
      *(bf16x8*)(vdst + (k8 << 3)) = *(const bf16x8*)(vsrc + (k8 << 3));
    return;
  }

#pragma unroll
  for (int mi = 0; mi < 4; ++mi) {
#pragma unroll
    for (int ni = 0; ni < 4; ++ni) {
      int col = n0 + (wn << 6) + (ni << 4) + l15;
      int rbase = m0 + (wm << 6) + (mi << 4) + (hi << 2);
      if (EPI != 1) {
        float bb = bias[col];
        __bf16* C = (__bf16*)Cout + sC * bz;
#pragma unroll
        for (int j = 0; j < 4; ++j)
          C[(size_t)(rbase + j) * ldC + col] = (__bf16)(acc[mi][ni][j] + bb);
      } else {
        float* C = (float*)Cout + sC * bz;
        const float* R = resid + sR * bz;
#pragma unroll
        for (int j = 0; j < 4; ++j) {
          int row = rbase + j;
          C[(size_t)row * ldC + col] = acc[mi][ni][j] + bias[row] + R[(size_t)row * ldC + col];
        }
      }
    }
  }
}

// ---------- attention (R14 structure + T5 setprio); K from kvK[n][s][1024] --
__global__ __launch_bounds__(256, 2) void attn_kernel(
    const __bf16* __restrict__ QT,   // [n][1024][1024]
    const __bf16* __restrict__ kvK,  // [n][256][1024] (K only)
    const __bf16* __restrict__ vT,   // [n][1024][256]
    const int* __restrict__ padding, // [n][256]
    __bf16* __restrict__ yT) {       // [n][1024][1024]
  int h = blockIdx.x, qb = blockIdx.y, n = blockIdx.z;
  int tid = threadIdx.x;
  int w = tid >> 6, lane = tid & 63;
  int l15 = lane & 15, hi = lane >> 4;
  int xk = (l15 & 7) << 3;

  __shared__ __align__(16) __bf16 lKP[256 * 64];  // K; later P [64 q][256 keys]
  __shared__ __align__(16) __bf16 lVt[64 * 256];  // V^T [64 d][256 keys]
  __shared__ __align__(16) float lpad[256];

  const __bf16* kvb = kvK + ((size_t)n << 18);
#pragma unroll
  for (int i = 0; i < 8; ++i) {
    int e = ((i << 8) + tid) << 3;
    int r = e >> 6;
    int c = e & 63;
    int cs = c ^ ((r & 7) << 3);
    gload_lds16(kvb + ((size_t)r << 10) + (h << 6) + cs, &lKP[e]);
  }
  const __bf16* vtb = vT + (((size_t)(n << 10) + (h << 6)) << 8);
#pragma unroll
  for (int i = 0; i < 8; ++i) {
    int e = ((i << 8) + tid) << 3;
    int r = e >> 8;
    int c = e & 255;
    int cs = c ^ ((r & 7) << 3);
    gload_lds16(vtb + ((size_t)r << 8) + cs, &lVt[e]);
  }
  lpad[tid] = 14426.95041f * (float)padding[(n << 8) + tid];  // 10000*log2(e)

  int q0w = (qb << 6) + (w << 4);
  const __bf16* qsrc = QT + ((size_t)((n << 10) + q0w + l15) << 10) + (h << 6) + (hi << 3);
  bf16x8 bq0 = *(const bf16x8*)qsrc;
  bf16x8 bq1 = *(const bf16x8*)(qsrc + 32);
  __syncthreads();

  f32x4 sa[16];
  __builtin_amdgcn_s_setprio(1);
#pragma unroll
  for (int kg = 0; kg < 16; ++kg) {
    const __bf16* krow = &lKP[((kg << 4) + l15) << 6];
    bf16x8 a0 = *(const bf16x8*)&krow[(hi << 3) ^ xk];
    bf16x8 a1 = *(const bf16x8*)&krow[(32 + (hi << 3)) ^ xk];
    f32x4 z = {0.f, 0.f, 0.f, 0.f};
    z = mfma16(a0, bq0, z);
    sa[kg] = mfma16(a1, bq1, z);
  }
  __builtin_amdgcn_s_setprio(0);

  // masked softmax in log2 domain (lane holds keys 16kg+4hi+j for q=q0w+l15)
  const float sc = 0.18033688f;   // 0.125 * log2(e)
  float mx0 = -3.4e38f, mx1 = -3.4e38f;
#pragma unroll
  for (int kg = 0; kg < 16; ++kg) {
    f32x4 pm = *(const f32x4*)&lpad[(kg << 4) + (hi << 2)];
#pragma unroll
    for (int j = 0; j < 4; ++j)
      sa[kg][j] = fmaf(sa[kg][j], sc, -pm[j]);
    mx0 = fmaxf(mx0, fmaxf(sa[kg][0], sa[kg][1]));
    mx1 = fmaxf(mx1, fmaxf(sa[kg][2], sa[kg][3]));
  }
  float mx = fmaxf(mx0, mx1);
  mx = fmaxf(mx, __shfl_xor(mx, 16));
  mx = fmaxf(mx, __shfl_xor(mx, 32));
  float sum = 0.f;
#pragma unroll
  for (int kg = 0; kg < 16; ++kg)
#pragma unroll
    for (int j = 0; j < 4; ++j) {
      float p = __builtin_amdgcn_exp2f(sa[kg][j] - mx);  // bare v_exp_f32
      sa[kg][j] = p;
      sum += p;
    }
  sum += __shfl_xor(sum, 16);
  sum += __shfl_xor(sum, 32);
  float dinv = 1.f / sum;

  __syncthreads();          // all waves done reading K -> lKP becomes P

  __bf16* lP = &lKP[(((w << 4) + l15) << 8)];
#pragma unroll
  for (int kg = 0; kg < 16; ++kg) {
    bf16x4 pk;
#pragma unroll
    for (int j = 0; j < 4; ++j) pk[j] = (__bf16)sa[kg][j];
    *(bf16x4*)&lP[(((kg << 4) + (hi << 2)) ^ xk)] = pk;
  }

  f32x4 ya[4] = {};
  __builtin_amdgcn_s_setprio(1);
#pragma unroll
  for (int kc = 0; kc < 8; ++kc) {
    bf16x8 pa = *(const bf16x8*)&lP[(((kc << 5) + (hi << 3)) ^ xk)];
#pragma unroll
    for (int nd = 0; nd < 4; ++nd) {
      bf16x8 vb = *(const bf16x8*)&lVt[(((nd << 4) + l15) << 8) + (((kc << 5) + (hi << 3)) ^ xk)];
      ya[nd] = mfma16(pa, vb, ya[nd]);
    }
  }
  __builtin_amdgcn_s_setprio(0);

  float dq[4];
#pragma unroll
  for (int j = 0; j < 4; ++j) dq[j] = __shfl(dinv, (hi << 2) + j);

#pragma unroll
  for (int nd = 0; nd < 4; ++nd) {
    int d = (h << 6) + (nd << 4) + l15;
#pragma unroll
    for (int j = 0; j < 4; ++j) {
      int q = q0w + (hi << 2) + j;
      yT[((size_t)((n << 10) + q) << 10) + d] = (__bf16)(ya[nd][j] * dq[j]);
    }
  }
}

extern "C" void kernel_launch(void* const* d_in, const int* in_sizes, int n_in,
                              void* d_out, int out_size, void* d_ws, size_t ws_size,
                              hipStream_t stream) {
  const float* x         = (const float*)d_in[0];
  const float* enc       = (const float*)d_in[1];
  const int*   padding   = (const int*)d_in[2];
  const float* gamma_dec = (const float*)d_in[3];
  const float* beta_dec  = (const float*)d_in[4];
  const float* gamma_enc = (const float*)d_in[5];
  const float* beta_enc  = (const float*)d_in[6];
  const float* Wq        = (const float*)d_in[7];
  const float* bq        = (const float*)d_in[8];
  const float* Wkv       = (const float*)d_in[9];
  const float* bkv       = (const float*)d_in[10];
  const float* Wo        = (const float*)d_in[11];
  const float* bo        = (const float*)d_in[12];
  float* out = (float*)d_out;

  char* ws = (char*)d_ws;
  // layout: ndT/yT 0..32M | QT 32..64M | kvK 64..72M | vT 72..80M |
  //         encn 80..86M | WqB | WkvB | WoB  (total < 95.5 MB, all disjoint)
  __bf16* ndT  = (__bf16*)(ws);
  __bf16* yT   = (__bf16*)(ws);                 // reuse: ndT dead after Q-GEMM
  __bf16* QT   = (__bf16*)(ws + 33554432);
  __bf16* kvK  = (__bf16*)(ws + 67108864);
  __bf16* vT   = (__bf16*)(ws + 75497472);
  __bf16* encn = (__bf16*)(ws + 83886080);
  __bf16* WqB  = (__bf16*)(ws + 92274688);
  __bf16* WkvB = (__bf16*)(ws + 94371840);
  __bf16* WoB  = (__bf16*)(ws + 97517568);

  ln_fused_kernel<<<dim3(16, 16), 1024, 0, stream>>>(x, gamma_dec, beta_dec, ndT);
  enc_ln_kernel<<<dim3(256, 16), 256, 0, stream>>>(enc, gamma_enc, beta_enc, encn);
  cast3_kernel<<<1024, 256, 0, stream>>>(Wq, WqB, 1024 * 1024,
                                         Wkv, WkvB, 2048 * 768,
                                         Wo, WoB, 1024 * 1024);

  // QT[n][p][o] = ndT[n] @ Wq^T + bq
  gemm128_kernel<0><<<dim3(8, 8, 16), 256, 0, stream>>>(
      ndT, WqB, bq, nullptr, QT, nullptr, 1024, 1024, 1024, 1024,
      (size_t)1024 * 1024, 0, (size_t)1024 * 1024, 0);
  // kv GEMM: K-half -> kvK[n][s][1024] (ldC=1024); V-half -> vT[n][c][s]
  gemm128_kernel<2><<<dim3(16, 2, 16), 256, 0, stream>>>(
      encn, WkvB, bkv, nullptr, kvK, vT, 256, 2048, 768, 1024,
      (size_t)256 * 768, 0, (size_t)256 * 1024, 0);

  attn_kernel<<<dim3(16, 16, 16), 256, 0, stream>>>(QT, kvK, vT, padding, yT);

  // out[n][o][p] = x + Wo @ y + bo   (A=WoB shared, Bt=yT per n)
  gemm128_kernel<1><<<dim3(8, 8, 16), 256, 0, stream>>>(
      WoB, yT, bo, x, out, nullptr, 1024, 1024, 1024, 1024,
      0, (size_t)1024 * 1024, (size_t)1024 * 1024, (size_t)1024 * 1024);
}